// Round 9
// baseline (244.898 us; speedup 1.0000x reference)
//
#include <hip/hip_runtime.h>

#define HW 4096
#define PCAP 1536u     // per-block LDS pre-candidate slots (expected ~1500)
#define FCAP 1024u     // per-block final candidate region (expected ~220)
#define OCAP 65536u    // global overflow list (safe superset path)

typedef short bf16x8 __attribute__((ext_vector_type(8)));
typedef float f32x16 __attribute__((ext_vector_type(16)));

__device__ __forceinline__ ushort f2bf_rne(float f) {
    unsigned u = __float_as_uint(f);
    return (ushort)((u + 0x7FFFu + ((u >> 16) & 1u)) >> 16);
}

// ---------------------------------------------------------------------------
// W transpose (Wt[c][o] = W[o][c]) + counter init folded in.
// ---------------------------------------------------------------------------
__global__ __launch_bounds__(256) void transpose_w_kernel(
    const float* __restrict__ Wm, float* __restrict__ Wt,
    unsigned* __restrict__ bcnt, unsigned* __restrict__ ocnt)
{
    const int o = blockIdx.x;        // 128
    const int c = threadIdx.x;       // 256
    Wt[c * 128 + o] = Wm[o * 256 + c];
    if (o < 2) bcnt[o * 256 + c] = 0u;
    if (o == 2 && c == 0) ocnt[0] = 0u;
}

// ---------------------------------------------------------------------------
// Kernel 1: 1x1-conv projection as an LDS-tiled vector GEMM (R8 structure,
// bitwise-identical outputs).  best[] zero-init folded into the z==0 path.
// Outputs: Qt/Pt fp32 [b][n][128], qnorm, bf16 packs in 32x32x16 fragment
// order: PK[b][t32][ks][lt][j] = proj[c=ks*16+(lt>>5)*8+j][n=t32*32+(lt&31)].
// ---------------------------------------------------------------------------
__global__ __launch_bounds__(256) void proj_kernel(
    const float* __restrict__ Fq, const float* __restrict__ Fp,
    const float* __restrict__ Wt, const float* __restrict__ bias,
    float* __restrict__ Qt, float* __restrict__ Pt,
    ushort* __restrict__ Qpk, ushort* __restrict__ Ppk,
    float* __restrict__ qnorm, unsigned long long* __restrict__ best)
{
    __shared__ float Ws[64][128];    // 32 KB
    __shared__ float Xs[64][64];     // 16 KB
    __shared__ float psum[16][68];

    const int tid = threadIdx.x;
    const int z  = blockIdx.z;                 // 0: q, 1: p
    const float* __restrict__ X = z ? Fp : Fq;
    const int b  = blockIdx.y;
    const int n0 = blockIdx.x * 64;
    const int og = tid >> 4;                   // 8 o's
    const int ng = tid & 15;                   // 4 n's

    float acc[4][8];
    #pragma unroll
    for (int i = 0; i < 4; ++i)
        #pragma unroll
        for (int j = 0; j < 8; ++j) acc[i][j] = 0.f;

    for (int cc = 0; cc < 4; ++cc) {
        __syncthreads();
        {
            const float4* src = (const float4*)(Wt + (size_t)cc * 64 * 128);
            float4* dst = (float4*)Ws;
            #pragma unroll
            for (int it = 0; it < 8; ++it) dst[it * 256 + tid] = src[it * 256 + tid];
        }
        #pragma unroll
        for (int it = 0; it < 4; ++it) {
            int f = it * 256 + tid;
            int r = f >> 4, n4 = f & 15;
            *(float4*)&Xs[r][n4 * 4] =
                *(const float4*)&X[(size_t)(b * 256 + cc * 64 + r) * HW + n0 + n4 * 4];
        }
        __syncthreads();

        for (int r = 0; r < 64; ++r) {
            float4 w0 = *(const float4*)&Ws[r][og * 8];
            float4 w1 = *(const float4*)&Ws[r][og * 8 + 4];
            float4 xv = *(const float4*)&Xs[r][ng * 4];
            float wa[8] = {w0.x, w0.y, w0.z, w0.w, w1.x, w1.y, w1.z, w1.w};
            float xa[4] = {xv.x, xv.y, xv.z, xv.w};
            #pragma unroll
            for (int i = 0; i < 4; ++i)
                #pragma unroll
                for (int j = 0; j < 8; ++j)
                    acc[i][j] += wa[j] * xa[i];
        }
    }

    {
        float4 b0 = *(const float4*)&bias[og * 8];
        float4 b1 = *(const float4*)&bias[og * 8 + 4];
        float ba[8] = {b0.x, b0.y, b0.z, b0.w, b1.x, b1.y, b1.z, b1.w};
        #pragma unroll
        for (int i = 0; i < 4; ++i)
            #pragma unroll
            for (int j = 0; j < 8; ++j) acc[i][j] += ba[j];
    }

    #pragma unroll
    for (int i = 0; i < 4; ++i) {
        float s = 0.f;
        #pragma unroll
        for (int j = 0; j < 8; ++j) s += acc[i][j] * acc[i][j];
        psum[og][ng * 4 + i] = s;
    }
    __syncthreads();
    float tot[4];
    #pragma unroll
    for (int i = 0; i < 4; ++i) {
        float s = 0.f;
        #pragma unroll
        for (int g = 0; g < 16; ++g) s += psum[g][ng * 4 + i];
        tot[i] = s;
    }

    if (z) {
        #pragma unroll
        for (int i = 0; i < 4; ++i) {
            float s = 1.0f / sqrtf(tot[i]);
            #pragma unroll
            for (int j = 0; j < 8; ++j) acc[i][j] *= s;
        }
    } else {
        if (og == 0) {
            #pragma unroll
            for (int i = 0; i < 4; ++i)
                qnorm[b * HW + n0 + ng * 4 + i] = sqrtf(tot[i]);
        }
        if (og == 1) {
            #pragma unroll
            for (int i = 0; i < 4; ++i)
                best[(size_t)b * HW + n0 + ng * 4 + i] = 0ull;
        }
    }

    {
        float* __restrict__ T = z ? Pt : Qt;
        #pragma unroll
        for (int i = 0; i < 4; ++i) {
            size_t tb = ((size_t)b * HW + n0 + ng * 4 + i) * 128 + og * 8;
            *(float4*)&T[tb]     = make_float4(acc[i][0], acc[i][1], acc[i][2], acc[i][3]);
            *(float4*)&T[tb + 4] = make_float4(acc[i][4], acc[i][5], acc[i][6], acc[i][7]);
        }
    }
    {
        ushort* __restrict__ PK = z ? Ppk : Qpk;
        const int ks = og >> 1;
        #pragma unroll
        for (int i = 0; i < 4; ++i) {
            const int na  = n0 + ng * 4 + i;
            const int t32 = na >> 5;
            const int lt  = (na & 31) + 32 * (og & 1);
            ushort u[8];
            #pragma unroll
            for (int k = 0; k < 8; ++k) u[k] = f2bf_rne(acc[i][k]);
            size_t pk = ((((size_t)b * 128 + t32) * 8 + ks) * 64 + lt) * 8;
            uint4 w;
            w.x = (unsigned)u[0] | ((unsigned)u[1] << 16);
            w.y = (unsigned)u[2] | ((unsigned)u[3] << 16);
            w.z = (unsigned)u[4] | ((unsigned)u[5] << 16);
            w.w = (unsigned)u[6] | ((unsigned)u[7] << 16);
            *(uint4*)&PK[pk] = w;
        }
    }
}

// ---------------------------------------------------------------------------
// SINGLE-PASS MFMA sim + candidate emit.  Grid (32,4,4): block = 128n x 1024m.
// Provable two-level filter (margin marg = 0.016||q||+1e-6 >= 2*delta,
// delta = bf16 rounding bound 0.00787||q||):
//   level 1 (per 128-m chunk): emit s >= chunkmax(row) - marg into LDS
//     (with score).  For any set S containing the true argmax m*:
//     s_bf16(m*) >= s_f32(m*) - d >= s_f32(argmax_bf16 in S) - d
//                >= max_bf16(S) - 2d -- so m* always passes.
//   level 2 (block): re-filter pre-candidates against the 1024-m row max.
// Pre-cap overflow bypasses level 2 straight to the overflow list (emitting
// a superset is always safe).  a-frags register-cached per chunk (40 vs 64
// ds_read_b128 per chunk per wave).
// D mapping: m = lane&31, row = (r&3)+8*(r>>2)+4*(lane>>5).
// ---------------------------------------------------------------------------
__global__ __launch_bounds__(256, 2) void sim_kernel(
    const ushort* __restrict__ Qpk, const ushort* __restrict__ Ppk,
    const float* __restrict__ qnorm,
    unsigned* __restrict__ cand, unsigned* __restrict__ bcnt,
    unsigned* __restrict__ ocand, unsigned* __restrict__ ocnt)
{
    __shared__ ushort Qs[16384];        // 32 KB
    __shared__ ushort Bs[16384];        // 32 KB
    __shared__ unsigned pre_enc[PCAP];  // 6 KB
    __shared__ float    pre_val[PCAP];  // 6 KB
    __shared__ float rowmax[128];
    __shared__ float margld[128];
    __shared__ unsigned pre_cnt, fin_cnt;

    const int tid  = threadIdx.x;
    const int lane = tid & 63;
    const int w    = tid >> 6;
    const int nb   = blockIdx.x;   // 32
    const int b    = blockIdx.y;   // 4
    const int ms   = blockIdx.z;   // 4
    const int blk  = nb + 32 * (b + 4 * ms);   // 512

    if (tid == 0) { pre_cnt = 0u; fin_cnt = 0u; }

    {
        const uint4* src = (const uint4*)(Qpk + ((size_t)b * 128 + nb * 4) * 4096);
        uint4* dst = (uint4*)Qs;
        #pragma unroll
        for (int it = 0; it < 8; ++it) dst[it * 256 + tid] = src[it * 256 + tid];
    }

    float marg[16];
    #pragma unroll
    for (int r = 0; r < 16; ++r) {
        int nl_ = (r & 3) + 8 * (r >> 2) + 4 * (lane >> 5);
        marg[r] = 0.016f * qnorm[b * HW + nb * 128 + w * 32 + nl_] + 1e-6f;
    }

    float bestv[16];
    #pragma unroll
    for (int r = 0; r < 16; ++r) bestv[r] = -1e30f;

    for (int ch = 0; ch < 8; ++ch) {
        __syncthreads();   // orders counter init, Qs stage, prior Bs reads
        {
            const uint4* src = (const uint4*)(Ppk +
                ((size_t)b * 128 + ms * 32 + ch * 4) * 4096);
            uint4* dst = (uint4*)Bs;
            #pragma unroll
            for (int it = 0; it < 8; ++it) dst[it * 256 + tid] = src[it * 256 + tid];
        }
        __syncthreads();

        // a-fragments for this wave's n-tile, all 8 k-steps (32 VGPR)
        bf16x8 af[8];
        #pragma unroll
        for (int ks = 0; ks < 8; ++ks)
            af[ks] = *(const bf16x8*)&Qs[((w * 8 + ks) * 64 + lane) * 8];

        f32x16 accbuf[4];
        #pragma unroll
        for (int mtl = 0; mtl < 4; ++mtl) {
            f32x16 acc;
            #pragma unroll
            for (int r = 0; r < 16; ++r) acc[r] = 0.f;
            #pragma unroll
            for (int ks = 0; ks < 8; ++ks) {
                bf16x8 bb = *(const bf16x8*)&Bs[((mtl * 8 + ks) * 64 + lane) * 8];
                acc = __builtin_amdgcn_mfma_f32_32x32x16_bf16(af[ks], bb, acc, 0, 0, 0);
            }
            accbuf[mtl] = acc;
        }

        #pragma unroll
        for (int r = 0; r < 16; ++r) {
            float mx = fmaxf(fmaxf(accbuf[0][r], accbuf[1][r]),
                             fmaxf(accbuf[2][r], accbuf[3][r]));
            #pragma unroll
            for (int d = 1; d < 32; d <<= 1)
                mx = fmaxf(mx, __shfl_xor(mx, d, 64));
            bestv[r] = fmaxf(bestv[r], mx);
            const float th = mx - marg[r];
            const int nl_ = (r & 3) + 8 * (r >> 2) + 4 * (lane >> 5);
            const int na = nb * 128 + w * 32 + nl_;
            #pragma unroll
            for (int mtl = 0; mtl < 4; ++mtl) {
                if (accbuf[mtl][r] >= th) {
                    const int m = ms * 1024 + ch * 128 + mtl * 32 + (lane & 31);
                    unsigned enc = ((unsigned)b << 24) | ((unsigned)na << 12) | (unsigned)m;
                    unsigned pos = atomicAdd(&pre_cnt, 1u);
                    if (pos < PCAP) {
                        pre_enc[pos] = enc;
                        pre_val[pos] = accbuf[mtl][r];
                    } else {   // safe superset path, no block filter
                        unsigned op = atomicAdd(ocnt, 1u);
                        if (op < OCAP) ocand[op] = enc;
                    }
                }
            }
        }
    }

    // publish per-row block maxima (uniform across each 32-lane half)
    #pragma unroll
    for (int r = 0; r < 16; ++r) {
        if ((lane & 31) == 0) {
            int nl_ = (r & 3) + 8 * (r >> 2) + 4 * (lane >> 5);
            rowmax[w * 32 + nl_] = bestv[r];
            margld[w * 32 + nl_] = marg[r];
        }
    }
    __syncthreads();

    unsigned pcnt = pre_cnt < PCAP ? pre_cnt : PCAP;
    for (unsigned i = tid; i < pcnt; i += 256) {
        unsigned enc = pre_enc[i];
        float v = pre_val[i];
        int row = (enc >> 12) & 127;   // na & 127 (nb*128-aligned base)
        if (v >= rowmax[row] - margld[row]) {
            unsigned pos = atomicAdd(&fin_cnt, 1u);
            if (pos < FCAP) {
                cand[(size_t)blk * FCAP + pos] = enc;
            } else {
                unsigned op = atomicAdd(ocnt, 1u);
                if (op < OCAP) ocand[op] = enc;
            }
        }
    }
    __syncthreads();
    if (tid == 0) bcnt[blk] = fin_cnt < FCAP ? fin_cnt : FCAP;
}

// ---------------------------------------------------------------------------
// exact fp32 rescore (sequential-c fma chain, unchanged ordering).  Block j
// consumes region j, then grid-strides overflow.  Packed u64 atomicMax.
// ---------------------------------------------------------------------------
__device__ __forceinline__ void rescore_one(
    const float* __restrict__ Qt, const float* __restrict__ Pt,
    unsigned c, unsigned long long* __restrict__ best)
{
    int m = c & 0xFFF, n = (c >> 12) & 0xFFF, b = c >> 24;
    const float* __restrict__ q = Qt + ((size_t)b * HW + n) * 128;
    const float* __restrict__ p = Pt + ((size_t)b * HW + m) * 128;
    float acc = 0.f;
    for (int k = 0; k < 128; ++k) acc += q[k] * p[k];
    unsigned u = __float_as_uint(acc);
    unsigned kk = (u & 0x80000000u) ? ~u : (u | 0x80000000u);
    unsigned long long key = ((unsigned long long)kk << 32) | (unsigned)(4095 - m);
    atomicMax(&best[(size_t)b * HW + n], key);
}

__global__ __launch_bounds__(256) void rescore_kernel(
    const float* __restrict__ Qt, const float* __restrict__ Pt,
    const unsigned* __restrict__ cand, const unsigned* __restrict__ bcnt,
    const unsigned* __restrict__ ocand, const unsigned* __restrict__ ocnt,
    unsigned long long* __restrict__ best)
{
    const int blk = blockIdx.x;          // 512
    const int tid = threadIdx.x;
    unsigned cnt = bcnt[blk];
    for (unsigned i = tid; i < cnt; i += 256)
        rescore_one(Qt, Pt, cand[(size_t)blk * FCAP + i], best);

    unsigned total = ocnt[0];
    if (total > OCAP) total = OCAP;
    for (unsigned i = blk * 256 + tid; i < total; i += 512 * 256)
        rescore_one(Qt, Pt, ocand[i], best);
}

// ---------------------------------------------------------------------------
// gather: out[b][c][n] = Fp[b][c][m(n)]; stage each 16 KB Fp row in LDS.
// ---------------------------------------------------------------------------
__global__ __launch_bounds__(256) void gather_kernel(
    const float* __restrict__ Fp, const unsigned long long* __restrict__ best,
    float* __restrict__ out)
{
    __shared__ float row[4096];
    const int blk = blockIdx.x;      // 1024 = 4b x 256c
    const int c = blk & 255;
    const int b = blk >> 8;
    const int tid = threadIdx.x;

    const float* __restrict__ src = Fp + ((size_t)b * 256 + c) * HW;
    #pragma unroll
    for (int it = 0; it < 4; ++it) {
        int f = it * 256 + tid;
        *(float4*)&row[f * 4] = *(const float4*)&src[f * 4];
    }
    __syncthreads();

    float* __restrict__ dst = out + ((size_t)b * 256 + c) * HW;
    #pragma unroll
    for (int it = 0; it < 16; ++it) {
        int n = it * 256 + tid;
        int m = 4095 - (int)(best[(size_t)b * HW + n] & 0xFFFull);
        dst[n] = row[m];
    }
}

extern "C" void kernel_launch(void* const* d_in, const int* in_sizes, int n_in,
                              void* d_out, int out_size, void* d_ws, size_t ws_size,
                              hipStream_t stream) {
    const float* Fq   = (const float*)d_in[0];
    const float* Fp   = (const float*)d_in[1];
    const float* Wm   = (const float*)d_in[2];
    const float* bias = (const float*)d_in[3];
    float* out = (float*)d_out;

    char* base = (char*)d_ws;
    float*  Qt    = (float*)(base);                               // 8 MB
    float*  Pt    = (float*)(base + (8u << 20));                  // 8 MB
    ushort* Qpk   = (ushort*)(base + (16u << 20));                // 4 MB
    ushort* Ppk   = (ushort*)(base + (20u << 20));                // 4 MB
    char* x = base + (24u << 20);
    float*  qnorm = (float*)x;              x += 65536;           // 64 KB
    unsigned long long* best = (unsigned long long*)x; x += 131072; // 128 KB
    unsigned* bcnt = (unsigned*)x;          x += 4096;            // 512 u32
    unsigned* ocnt = (unsigned*)x;          x += 16;
    unsigned* cand = (unsigned*)x;          x += (size_t)512 * FCAP * 4; // 2 MB
    unsigned* ocand = (unsigned*)x;         x += OCAP * 4;        // 256 KB
    float*  Wtg   = (float*)x;                                    // 128 KB

    transpose_w_kernel<<<128, 256, 0, stream>>>(Wm, Wtg, bcnt, ocnt);
    proj_kernel<<<dim3(64, 4, 2), 256, 0, stream>>>(Fq, Fp, Wtg, bias,
                                                    Qt, Pt, Qpk, Ppk, qnorm, best);
    sim_kernel<<<dim3(32, 4, 4), 256, 0, stream>>>(Qpk, Ppk, qnorm,
                                                   cand, bcnt, ocand, ocnt);
    rescore_kernel<<<512, 256, 0, stream>>>(Qt, Pt, cand, bcnt, ocand, ocnt, best);
    gather_kernel<<<1024, 256, 0, stream>>>(Fp, best, out);
}

// Round 10
// 221.808 us; speedup vs baseline: 1.1041x; 1.1041x over previous
//
#include <hip/hip_runtime.h>

#define HW 4096
#define PCAP 2048u     // per-block LDS pre-candidate slots (expected ~1610)
#define FCAP 1024u     // per-block final candidate region (expected ~224)
#define OVCAP 1024u    // per-block overflow region (expected 0 used)

typedef short bf16x8 __attribute__((ext_vector_type(8)));
typedef float f32x16 __attribute__((ext_vector_type(16)));

__device__ __forceinline__ ushort f2bf_rne(float f) {
    unsigned u = __float_as_uint(f);
    return (ushort)((u + 0x7FFFu + ((u >> 16) & 1u)) >> 16);
}

// ---------------------------------------------------------------------------
// W transpose (Wt[c][o] = W[o][c]) + per-block counter init folded in.
// ---------------------------------------------------------------------------
__global__ __launch_bounds__(256) void transpose_w_kernel(
    const float* __restrict__ Wm, float* __restrict__ Wt,
    unsigned* __restrict__ bcnt, unsigned* __restrict__ obcnt)
{
    const int o = blockIdx.x;        // 128
    const int c = threadIdx.x;       // 256
    Wt[c * 128 + o] = Wm[o * 256 + c];
    if (o < 2)             bcnt [o * 256 + c] = 0u;
    else if (o < 4)        obcnt[(o - 2) * 256 + c] = 0u;
}

// ---------------------------------------------------------------------------
// Kernel 1: 1x1-conv projection as an LDS-tiled vector GEMM (R8/R9 structure,
// bitwise-identical outputs).  best[] zero-init folded into the z==0 path.
// Outputs: Qt/Pt fp32 [b][n][128], qnorm, bf16 packs in 32x32x16 fragment
// order: PK[b][t32][ks][lt][j] = proj[c=ks*16+(lt>>5)*8+j][n=t32*32+(lt&31)].
// ---------------------------------------------------------------------------
__global__ __launch_bounds__(256) void proj_kernel(
    const float* __restrict__ Fq, const float* __restrict__ Fp,
    const float* __restrict__ Wt, const float* __restrict__ bias,
    float* __restrict__ Qt, float* __restrict__ Pt,
    ushort* __restrict__ Qpk, ushort* __restrict__ Ppk,
    float* __restrict__ qnorm, unsigned long long* __restrict__ best)
{
    __shared__ float Ws[64][128];    // 32 KB
    __shared__ float Xs[64][64];     // 16 KB
    __shared__ float psum[16][68];

    const int tid = threadIdx.x;
    const int z  = blockIdx.z;                 // 0: q, 1: p
    const float* __restrict__ X = z ? Fp : Fq;
    const int b  = blockIdx.y;
    const int n0 = blockIdx.x * 64;
    const int og = tid >> 4;                   // 8 o's
    const int ng = tid & 15;                   // 4 n's

    float acc[4][8];
    #pragma unroll
    for (int i = 0; i < 4; ++i)
        #pragma unroll
        for (int j = 0; j < 8; ++j) acc[i][j] = 0.f;

    for (int cc = 0; cc < 4; ++cc) {
        __syncthreads();
        {
            const float4* src = (const float4*)(Wt + (size_t)cc * 64 * 128);
            float4* dst = (float4*)Ws;
            #pragma unroll
            for (int it = 0; it < 8; ++it) dst[it * 256 + tid] = src[it * 256 + tid];
        }
        #pragma unroll
        for (int it = 0; it < 4; ++it) {
            int f = it * 256 + tid;
            int r = f >> 4, n4 = f & 15;
            *(float4*)&Xs[r][n4 * 4] =
                *(const float4*)&X[(size_t)(b * 256 + cc * 64 + r) * HW + n0 + n4 * 4];
        }
        __syncthreads();

        for (int r = 0; r < 64; ++r) {
            float4 w0 = *(const float4*)&Ws[r][og * 8];
            float4 w1 = *(const float4*)&Ws[r][og * 8 + 4];
            float4 xv = *(const float4*)&Xs[r][ng * 4];
            float wa[8] = {w0.x, w0.y, w0.z, w0.w, w1.x, w1.y, w1.z, w1.w};
            float xa[4] = {xv.x, xv.y, xv.z, xv.w};
            #pragma unroll
            for (int i = 0; i < 4; ++i)
                #pragma unroll
                for (int j = 0; j < 8; ++j)
                    acc[i][j] += wa[j] * xa[i];
        }
    }

    {
        float4 b0 = *(const float4*)&bias[og * 8];
        float4 b1 = *(const float4*)&bias[og * 8 + 4];
        float ba[8] = {b0.x, b0.y, b0.z, b0.w, b1.x, b1.y, b1.z, b1.w};
        #pragma unroll
        for (int i = 0; i < 4; ++i)
            #pragma unroll
            for (int j = 0; j < 8; ++j) acc[i][j] += ba[j];
    }

    #pragma unroll
    for (int i = 0; i < 4; ++i) {
        float s = 0.f;
        #pragma unroll
        for (int j = 0; j < 8; ++j) s += acc[i][j] * acc[i][j];
        psum[og][ng * 4 + i] = s;
    }
    __syncthreads();
    float tot[4];
    #pragma unroll
    for (int i = 0; i < 4; ++i) {
        float s = 0.f;
        #pragma unroll
        for (int g = 0; g < 16; ++g) s += psum[g][ng * 4 + i];
        tot[i] = s;
    }

    if (z) {
        #pragma unroll
        for (int i = 0; i < 4; ++i) {
            float s = 1.0f / sqrtf(tot[i]);
            #pragma unroll
            for (int j = 0; j < 8; ++j) acc[i][j] *= s;
        }
    } else {
        if (og == 0) {
            #pragma unroll
            for (int i = 0; i < 4; ++i)
                qnorm[b * HW + n0 + ng * 4 + i] = sqrtf(tot[i]);
        }
        if (og == 1) {
            #pragma unroll
            for (int i = 0; i < 4; ++i)
                best[(size_t)b * HW + n0 + ng * 4 + i] = 0ull;
        }
    }

    {
        float* __restrict__ T = z ? Pt : Qt;
        #pragma unroll
        for (int i = 0; i < 4; ++i) {
            size_t tb = ((size_t)b * HW + n0 + ng * 4 + i) * 128 + og * 8;
            *(float4*)&T[tb]     = make_float4(acc[i][0], acc[i][1], acc[i][2], acc[i][3]);
            *(float4*)&T[tb + 4] = make_float4(acc[i][4], acc[i][5], acc[i][6], acc[i][7]);
        }
    }
    {
        ushort* __restrict__ PK = z ? Ppk : Qpk;
        const int ks = og >> 1;
        #pragma unroll
        for (int i = 0; i < 4; ++i) {
            const int na  = n0 + ng * 4 + i;
            const int t32 = na >> 5;
            const int lt  = (na & 31) + 32 * (og & 1);
            ushort u[8];
            #pragma unroll
            for (int k = 0; k < 8; ++k) u[k] = f2bf_rne(acc[i][k]);
            size_t pk = ((((size_t)b * 128 + t32) * 8 + ks) * 64 + lt) * 8;
            uint4 w;
            w.x = (unsigned)u[0] | ((unsigned)u[1] << 16);
            w.y = (unsigned)u[2] | ((unsigned)u[3] << 16);
            w.z = (unsigned)u[4] | ((unsigned)u[5] << 16);
            w.w = (unsigned)u[6] | ((unsigned)u[7] << 16);
            *(uint4*)&PK[pk] = w;
        }
    }
}

// ---------------------------------------------------------------------------
// SINGLE-PASS MFMA sim + candidate emit.  Grid (32,4,4): block = 128n x 1024m.
// R9 fix: NO device-scope atomics anywhere.  Level-1 emit (s >= chunkmax -
// marg, marg = 0.016||q||+1e-6 >= 2*bf16-delta -- argmax provably retained)
// goes to a 2048-slot LDS buffer; the level-2 score is a 6-bit quantized
// deficit packed into enc: q6 = floor((chunkmax - v)/marg * 63), so
// v_upper = chunkmax - q6*marg/63 >= v (sound).  Level-2 keeps
// v_upper >= rowmax - marg (rowmax = this block's 1024-m row max).
// Overflow paths are per-block global regions with LDS counters.
// enc = q6<<26 | b<<24 | na<<12 | m  (q6 stripped before output).
// D mapping: m = lane&31, row = (r&3)+8*(r>>2)+4*(lane>>5).
// ---------------------------------------------------------------------------
__global__ __launch_bounds__(256, 2) void sim_kernel(
    const ushort* __restrict__ Qpk, const ushort* __restrict__ Ppk,
    const float* __restrict__ qnorm,
    unsigned* __restrict__ cand, unsigned* __restrict__ bcnt,
    unsigned* __restrict__ ocand, unsigned* __restrict__ obcnt)
{
    __shared__ ushort Qs[16384];        // 32 KB
    __shared__ ushort Bs[16384];        // 32 KB
    __shared__ unsigned pre_enc[PCAP];  // 8 KB
    __shared__ float chunkmax[8][128];  // 4 KB
    __shared__ float rowthr[128];       // rowmax - marg
    __shared__ float m63[128];          // marg/63
    __shared__ unsigned pre_cnt, fin_cnt, ovf_cnt;

    const int tid  = threadIdx.x;
    const int lane = tid & 63;
    const int w    = tid >> 6;
    const int nb   = blockIdx.x;   // 32
    const int b    = blockIdx.y;   // 4
    const int ms   = blockIdx.z;   // 4
    const int blk  = nb + 32 * (b + 4 * ms);   // 512

    if (tid == 0) { pre_cnt = 0u; fin_cnt = 0u; ovf_cnt = 0u; }

    {
        const uint4* src = (const uint4*)(Qpk + ((size_t)b * 128 + nb * 4) * 4096);
        uint4* dst = (uint4*)Qs;
        #pragma unroll
        for (int it = 0; it < 8; ++it) dst[it * 256 + tid] = src[it * 256 + tid];
    }
    __syncthreads();   // Qs visible (also orders counter init)

    // a-fragments: constant across all chunks -- load once (LDS-backed)
    bf16x8 af[8];
    #pragma unroll
    for (int ks = 0; ks < 8; ++ks)
        af[ks] = *(const bf16x8*)&Qs[((w * 8 + ks) * 64 + lane) * 8];

    float marg[16], im63[16];
    #pragma unroll
    for (int r = 0; r < 16; ++r) {
        int nl_ = (r & 3) + 8 * (r >> 2) + 4 * (lane >> 5);
        marg[r] = 0.016f * qnorm[b * HW + nb * 128 + w * 32 + nl_] + 1e-6f;
        im63[r] = 63.0f / marg[r];
    }

    float bestv[16];
    #pragma unroll
    for (int r = 0; r < 16; ++r) bestv[r] = -1e30f;

    for (int ch = 0; ch < 8; ++ch) {
        __syncthreads();   // prior chunk's Bs reads done
        {
            const uint4* src = (const uint4*)(Ppk +
                ((size_t)b * 128 + ms * 32 + ch * 4) * 4096);
            uint4* dst = (uint4*)Bs;
            #pragma unroll
            for (int it = 0; it < 8; ++it) dst[it * 256 + tid] = src[it * 256 + tid];
        }
        __syncthreads();

        f32x16 accbuf[4];
        #pragma unroll
        for (int mtl = 0; mtl < 4; ++mtl) {
            f32x16 acc;
            #pragma unroll
            for (int r = 0; r < 16; ++r) acc[r] = 0.f;
            #pragma unroll
            for (int ks = 0; ks < 8; ++ks) {
                bf16x8 bb = *(const bf16x8*)&Bs[((mtl * 8 + ks) * 64 + lane) * 8];
                acc = __builtin_amdgcn_mfma_f32_32x32x16_bf16(af[ks], bb, acc, 0, 0, 0);
            }
            accbuf[mtl] = acc;
        }

        #pragma unroll
        for (int r = 0; r < 16; ++r) {
            float mx = fmaxf(fmaxf(accbuf[0][r], accbuf[1][r]),
                             fmaxf(accbuf[2][r], accbuf[3][r]));
            #pragma unroll
            for (int d = 1; d < 32; d <<= 1)
                mx = fmaxf(mx, __shfl_xor(mx, d, 64));
            bestv[r] = fmaxf(bestv[r], mx);
            const int nl_ = (r & 3) + 8 * (r >> 2) + 4 * (lane >> 5);
            const int row = w * 32 + nl_;
            if ((lane & 31) == 0) chunkmax[ch][row] = mx;
            const float th = mx - marg[r];
            const int na = nb * 128 + row;
            #pragma unroll
            for (int mtl = 0; mtl < 4; ++mtl) {
                float v = accbuf[mtl][r];
                if (v >= th) {
                    unsigned q6 = (unsigned)fminf(63.0f, floorf((mx - v) * im63[r]));
                    const int m = ms * 1024 + ch * 128 + mtl * 32 + (lane & 31);
                    unsigned enc = (q6 << 26) | ((unsigned)b << 24) |
                                   ((unsigned)na << 12) | (unsigned)m;
                    unsigned pos = atomicAdd(&pre_cnt, 1u);   // LDS atomic
                    if (pos < PCAP) {
                        pre_enc[pos] = enc;
                    } else {   // per-block overflow, superset-safe, no filter
                        unsigned op = atomicAdd(&ovf_cnt, 1u);
                        if (op < OVCAP)
                            ocand[(size_t)blk * OVCAP + op] = enc & 0x03FFFFFFu;
                    }
                }
            }
        }
    }

    // publish per-row block thresholds
    #pragma unroll
    for (int r = 0; r < 16; ++r) {
        if ((lane & 31) == 0) {
            int nl_ = (r & 3) + 8 * (r >> 2) + 4 * (lane >> 5);
            rowthr[w * 32 + nl_] = bestv[r] - marg[r];
            m63[w * 32 + nl_]    = marg[r] * (1.0f / 63.0f);
        }
    }
    __syncthreads();

    // level-2 filter: keep iff v_upper >= rowmax - marg
    unsigned pcnt = pre_cnt < PCAP ? pre_cnt : PCAP;
    for (unsigned i = tid; i < pcnt; i += 256) {
        unsigned enc = pre_enc[i];
        unsigned q6 = enc >> 26;
        int row = (enc >> 12) & 127;
        int ch  = (enc >> 7) & 7;
        float v_upper = chunkmax[ch][row] - (float)q6 * m63[row];
        if (v_upper >= rowthr[row]) {
            unsigned pos = atomicAdd(&fin_cnt, 1u);
            if (pos < FCAP) {
                cand[(size_t)blk * FCAP + pos] = enc & 0x03FFFFFFu;
            } else {
                unsigned op = atomicAdd(&ovf_cnt, 1u);
                if (op < OVCAP)
                    ocand[(size_t)blk * OVCAP + op] = enc & 0x03FFFFFFu;
            }
        }
    }
    __syncthreads();
    if (tid == 0) {
        bcnt[blk]  = fin_cnt < FCAP ? fin_cnt : FCAP;
        obcnt[blk] = ovf_cnt < OVCAP ? ovf_cnt : OVCAP;
    }
}

// ---------------------------------------------------------------------------
// exact fp32 rescore (sequential-c fma chain, unchanged ordering).  Block j
// consumes its own region + its own overflow region.  Packed u64 atomicMax.
// ---------------------------------------------------------------------------
__device__ __forceinline__ void rescore_one(
    const float* __restrict__ Qt, const float* __restrict__ Pt,
    unsigned c, unsigned long long* __restrict__ best)
{
    int m = c & 0xFFF, n = (c >> 12) & 0xFFF, b = (c >> 24) & 3;
    const float* __restrict__ q = Qt + ((size_t)b * HW + n) * 128;
    const float* __restrict__ p = Pt + ((size_t)b * HW + m) * 128;
    float acc = 0.f;
    for (int k = 0; k < 128; ++k) acc += q[k] * p[k];
    unsigned u = __float_as_uint(acc);
    unsigned kk = (u & 0x80000000u) ? ~u : (u | 0x80000000u);
    unsigned long long key = ((unsigned long long)kk << 32) | (unsigned)(4095 - m);
    atomicMax(&best[(size_t)b * HW + n], key);
}

__global__ __launch_bounds__(256) void rescore_kernel(
    const float* __restrict__ Qt, const float* __restrict__ Pt,
    const unsigned* __restrict__ cand, const unsigned* __restrict__ bcnt,
    const unsigned* __restrict__ ocand, const unsigned* __restrict__ obcnt,
    unsigned long long* __restrict__ best)
{
    const int blk = blockIdx.x;          // 512
    const int tid = threadIdx.x;
    unsigned cnt = bcnt[blk];
    for (unsigned i = tid; i < cnt; i += 256)
        rescore_one(Qt, Pt, cand[(size_t)blk * FCAP + i], best);

    unsigned ocnt = obcnt[blk];
    for (unsigned i = tid; i < ocnt; i += 256)
        rescore_one(Qt, Pt, ocand[(size_t)blk * OVCAP + i], best);
}

// ---------------------------------------------------------------------------
// gather: out[b][c][n] = Fp[b][c][m(n)]; stage each 16 KB Fp row in LDS.
// ---------------------------------------------------------------------------
__global__ __launch_bounds__(256) void gather_kernel(
    const float* __restrict__ Fp, const unsigned long long* __restrict__ best,
    float* __restrict__ out)
{
    __shared__ float row[4096];
    const int blk = blockIdx.x;      // 1024 = 4b x 256c
    const int c = blk & 255;
    const int b = blk >> 8;
    const int tid = threadIdx.x;

    const float* __restrict__ src = Fp + ((size_t)b * 256 + c) * HW;
    #pragma unroll
    for (int it = 0; it < 4; ++it) {
        int f = it * 256 + tid;
        *(float4*)&row[f * 4] = *(const float4*)&src[f * 4];
    }
    __syncthreads();

    float* __restrict__ dst = out + ((size_t)b * 256 + c) * HW;
    #pragma unroll
    for (int it = 0; it < 16; ++it) {
        int n = it * 256 + tid;
        int m = 4095 - (int)(best[(size_t)b * HW + n] & 0xFFFull);
        dst[n] = row[m];
    }
}

extern "C" void kernel_launch(void* const* d_in, const int* in_sizes, int n_in,
                              void* d_out, int out_size, void* d_ws, size_t ws_size,
                              hipStream_t stream) {
    const float* Fq   = (const float*)d_in[0];
    const float* Fp   = (const float*)d_in[1];
    const float* Wm   = (const float*)d_in[2];
    const float* bias = (const float*)d_in[3];
    float* out = (float*)d_out;

    char* base = (char*)d_ws;
    float*  Qt    = (float*)(base);                               // 8 MB
    float*  Pt    = (float*)(base + (8u << 20));                  // 8 MB
    ushort* Qpk   = (ushort*)(base + (16u << 20));                // 4 MB
    ushort* Ppk   = (ushort*)(base + (20u << 20));                // 4 MB
    char* x = base + (24u << 20);
    float*  qnorm = (float*)x;              x += 65536;           // 64 KB
    unsigned long long* best = (unsigned long long*)x; x += 131072; // 128 KB
    unsigned* bcnt  = (unsigned*)x;         x += 2048;            // 512 u32
    unsigned* obcnt = (unsigned*)x;         x += 2048;            // 512 u32
    unsigned* cand  = (unsigned*)x;         x += (size_t)512 * FCAP * 4;  // 2 MB
    unsigned* ocand = (unsigned*)x;         x += (size_t)512 * OVCAP * 4; // 2 MB
    float*  Wtg   = (float*)x;                                    // 128 KB

    transpose_w_kernel<<<128, 256, 0, stream>>>(Wm, Wtg, bcnt, obcnt);
    proj_kernel<<<dim3(64, 4, 2), 256, 0, stream>>>(Fq, Fp, Wtg, bias,
                                                    Qt, Pt, Qpk, Ppk, qnorm, best);
    sim_kernel<<<dim3(32, 4, 4), 256, 0, stream>>>(Qpk, Ppk, qnorm,
                                                   cand, bcnt, ocand, obcnt);
    rescore_kernel<<<512, 256, 0, stream>>>(Qt, Pt, cand, bcnt, ocand, obcnt, best);
    gather_kernel<<<1024, 256, 0, stream>>>(Fp, best, out);
}